// Round 6
// baseline (215.783 us; speedup 1.0000x reference)
//
#include <hip/hip_runtime.h>

// Correlation via bf16 MFMA banded Gram.
// out[b, dyp*21+k, y, x] = (1/256) * sum_c in1[b,c,y,x] * in2[b,c,y+2(dyp-10), x+2(k-10)]
// Workspace layout: Ag/Bg[b*64+y][par*48+col][c] bf16, x = 2*col+par.

typedef short bf16x8 __attribute__((ext_vector_type(8)));
typedef float f32x4  __attribute__((ext_vector_type(4)));

#define PLANE 24576         // shorts per (b,y) plane: 96 rows * 256 c
#define BP    260           // padded B LDS row stride (shorts)

__device__ __forceinline__ short f2bf(float f) {
    union { float f; unsigned u; } x; x.f = f;
    const unsigned u = x.u;
    return (short)((u + 0x7fffu + ((u >> 16) & 1u)) >> 16);
}

// ---------- prepass: fp32 [b][c][y][x] -> bf16 [b*64+y][par*48+col][c] ----------
// block = (sel, b, ytile of 8, ctile of 64). LDS = 768 rows x 8 cells (16B),
// physical cell col = cx ^ ((xx>>2)&7): conflict-free writes, LINEAR reads.
__global__ __launch_bounds__(256)
void corr_prepass(const float* __restrict__ in1, const float* __restrict__ in2,
                  short* __restrict__ dstA, short* __restrict__ dstB) {
    const int bid = blockIdx.x;              // [0,256)
    const int sel = bid >> 7;
    const int r   = bid & 127;
    const int b   = r >> 5;
    const int yt  = (r >> 2) & 7;
    const int ct  = r & 3;
    const int c0 = ct * 64, y0 = yt * 8;
    const float* src = sel ? in2 : in1;
    short* dst = sel ? dstB : dstA;

    __shared__ __align__(16) short T[6144 * 8];   // 98304 B
    const int tid = threadIdx.x;

    // write phase: 1536 thread-slots, each converts 8 channels x 1 float4 -> 4 cells
#pragma unroll
    for (int it = 0; it < 6; ++it) {
        const int d = it * 256 + tid;            // [0,1536)
        const int g = d / 192;                   // channel octet 0..7 (wave-aligned)
        const int f = d - g * 192;               // float4 index in 8y*96x
        const int yy = f / 24;
        const int xf = 4 * (f - yy * 24);
        float4 v[8];
#pragma unroll
        for (int j = 0; j < 8; ++j) {
            const int c = c0 + g * 8 + j;
            v[j] = *(const float4*)(src + ((size_t)(b * 256 + c) * 64 + y0 + yy) * 96 + xf);
        }
        bf16x8 w0, w1, w2, w3;
#pragma unroll
        for (int j = 0; j < 8; ++j) {
            w0[j] = f2bf(v[j].x); w1[j] = f2bf(v[j].y);
            w2[j] = f2bf(v[j].z); w3[j] = f2bf(v[j].w);
        }
        const int pc = g ^ (f & 7);              // physical cell col for xx=4f..4f+3
        const int a0 = (4 * f) * 64 + pc * 8;    // shorts
        *(bf16x8*)&T[a0]       = w0;
        *(bf16x8*)&T[a0 + 64]  = w1;
        *(bf16x8*)&T[a0 + 128] = w2;
        *(bf16x8*)&T[a0 + 192] = w3;
    }
    __syncthreads();

    // read phase: linear LDS read, permuted-but-dense global store
#pragma unroll
    for (int it = 0; it < 24; ++it) {
        const int D  = it * 256 + tid;           // [0,6144)
        const int xx = D >> 3;
        const int pc = D & 7;
        const int cx = pc ^ ((xx >> 2) & 7);     // logical channel octet
        const bf16x8 w = *(const bf16x8*)&T[D * 8];
        const int yy = xx / 96;
        const int x  = xx - yy * 96;
        const int rl = (x & 1) * 48 + (x >> 1);  // par*48+col
        const size_t Rg = (size_t)(b * 64 + y0 + yy) * 96 + rl;
        *(bf16x8*)(dst + Rg * 256 + c0 + cx * 8) = w;
    }
}

// ---------- main kernel ----------
__global__ __launch_bounds__(256, 2)
void corr_mfma(const short* __restrict__ Ag, const short* __restrict__ Bg,
               float* __restrict__ out) {
    const int bid = blockIdx.x;                  // [0,1024)
    const int pg  = bid >> 8;                    // 0..3
    const int by2 = bid & 255;
    const int b = by2 >> 6, y2 = by2 & 63;
    const int p0 = pg * 3;
    const int p1 = (p0 + 3 < 11) ? (p0 + 3) : 11;

    const int tid  = threadIdx.x;
    const int lane = tid & 63, w = tid >> 6;
    const int par  = w & 1, slot = w >> 1;
    const int n    = lane & 15, q = lane >> 4;

    __shared__ __align__(16) short Bsh[96 * BP];     // 49920 B
    __shared__ __align__(16) float scr[2][21 * 97];  // 16296 B

    // stage B(b,y2) once
    {
        const short* src = Bg + (size_t)by2 * PLANE;
#pragma unroll
        for (int it = 0; it < 12; ++it) {
            const int j = it * 256 + tid;
            *(bf16x8*)&Bsh[(j >> 5) * BP + (j & 31) * 8] = *(const bf16x8*)(src + j * 8);
        }
    }
    __syncthreads();

    const bool v0 = (n >= 10), v3 = (n < 10);
    const int  r0c = v0 ? (n - 10) : 0;
    const int  r3c = v3 ? (n + 38) : 0;
    const short* Bp = &Bsh[par * 48 * BP];

    bf16x8 af[3][8];
    // preload A-fragments for p0
    {
        const int dyp = 2 * p0 + slot;
        const int yy  = y2 + 20 - 2 * dyp;
        if (dyp < 21 && yy >= 0 && yy < 64) {
            const short* Ap = Ag + ((size_t)(b * 64 + yy) * 96 + par * 48) * 256;
#pragma unroll
            for (int ks = 0; ks < 8; ++ks)
#pragma unroll
                for (int Xi = 0; Xi < 3; ++Xi)
                    af[Xi][ks] = *(const bf16x8*)(Ap + (Xi * 16 + n) * 256 + ks * 32 + q * 8);
        }
    }

    for (int p = p0; p < p1; ++p) {
        const int dyp = 2 * p + slot;
        const int y   = y2 + 20 - 2 * dyp;
        const bool live = (dyp < 21) && (y >= 0) && (y < 64);

        f32x4 acc[9];
#pragma unroll
        for (int t2 = 0; t2 < 9; ++t2) acc[t2] = (f32x4)0.0f;

        if (live) {
#pragma unroll
            for (int ks = 0; ks < 8; ++ks) {
                const int ko = ks * 32 + q * 8;
                bf16x8 b0 = *(const bf16x8*)&Bp[r0c * BP + ko];     if (!v0) b0 = 0;
                bf16x8 b1 = *(const bf16x8*)&Bp[(n + 6)  * BP + ko];
                bf16x8 b2 = *(const bf16x8*)&Bp[(n + 22) * BP + ko];
                bf16x8 b3 = *(const bf16x8*)&Bp[r3c * BP + ko];     if (!v3) b3 = 0;
                acc[0] = __builtin_amdgcn_mfma_f32_16x16x32_bf16(af[0][ks], b0, acc[0], 0, 0, 0);
                acc[1] = __builtin_amdgcn_mfma_f32_16x16x32_bf16(af[0][ks], b1, acc[1], 0, 0, 0);
                acc[2] = __builtin_amdgcn_mfma_f32_16x16x32_bf16(af[0][ks], b2, acc[2], 0, 0, 0);
                acc[3] = __builtin_amdgcn_mfma_f32_16x16x32_bf16(af[1][ks], b1, acc[3], 0, 0, 0);
                acc[4] = __builtin_amdgcn_mfma_f32_16x16x32_bf16(af[1][ks], b2, acc[4], 0, 0, 0);
                acc[5] = __builtin_amdgcn_mfma_f32_16x16x32_bf16(af[1][ks], b3, acc[5], 0, 0, 0);
                acc[6] = __builtin_amdgcn_mfma_f32_16x16x32_bf16(af[2][ks], b2, acc[6], 0, 0, 0);
                acc[7] = __builtin_amdgcn_mfma_f32_16x16x32_bf16(af[2][ks], b3, acc[7], 0, 0, 0);
                // acc[8] stays zero (B cols all OOB) but is scattered (real zeros)
            }
        }

        // prefetch next iteration's A-fragments; latency covered by scatter+store
        if (p + 1 < p1) {
            const int dn = 2 * (p + 1) + slot;
            const int yn = y2 + 20 - 2 * dn;
            if (dn < 21 && yn >= 0 && yn < 64) {
                const short* Ap = Ag + ((size_t)(b * 64 + yn) * 96 + par * 48) * 256;
#pragma unroll
                for (int ks = 0; ks < 8; ++ks)
#pragma unroll
                    for (int Xi = 0; Xi < 3; ++Xi)
                        af[Xi][ks] = *(const bf16x8*)(Ap + (Xi * 16 + n) * 256 + ks * 32 + q * 8);
            }
        }

        if (live) {
            float* sc = scr[slot];
            const int mb = q * 4;
#pragma unroll
            for (int t2 = 0; t2 < 9; ++t2) {
                const int Xi = (t2 < 3) ? 0 : (t2 < 6 ? 1 : 2);
                constexpr int UJ[9] = {0, 1, 2, 1, 2, 3, 2, 3, 4};
                const int ub = UJ[t2] * 16;
#pragma unroll
                for (int rr = 0; rr < 4; ++rr) {
                    const int xe = Xi * 16 + mb + rr;
                    const int k  = ub + n - xe;
                    if ((unsigned)k < 21u)
                        sc[k * 97 + 2 * xe + par] = acc[t2][rr];
                }
            }
        }
        __syncthreads();

#pragma unroll
        for (int it = 0; it < 16; ++it) {
            const int e = it * 256 + tid;        // [0,4096), valid < 4032
            if (e < 4032) {
                const int s  = e / 2016;
                const int f  = e - s * 2016;
                const int k  = f / 96;
                const int x  = f - k * 96;
                const int dd = 2 * p + s;
                const int yd = y2 + 20 - 2 * dd;
                if (dd < 21 && yd >= 0 && yd < 64)
                    out[((size_t)(b * 441 + dd * 21 + k) * 64 + yd) * 96 + x] =
                        scr[s][k * 97 + x] * (1.0f / 256.0f);
            }
        }
        __syncthreads();
    }
}

extern "C" void kernel_launch(void* const* d_in, const int* in_sizes, int n_in,
                              void* d_out, int out_size, void* d_ws, size_t ws_size,
                              hipStream_t stream) {
    const float* in1 = (const float*)d_in[0];
    const float* in2 = (const float*)d_in[1];
    float* out = (float*)d_out;

    short* Ag = (short*)d_ws;                    // 256 planes * 24576 shorts = 12.58 MB
    short* Bg = Ag + (size_t)256 * PLANE;        // 12.58 MB

    corr_prepass<<<dim3(256), dim3(256), 0, stream>>>(in1, in2, Ag, Bg);
    corr_mfma<<<dim3(1024), dim3(256), 0, stream>>>(Ag, Bg, out);
}

// Round 8
// 206.177 us; speedup vs baseline: 1.0466x; 1.0466x over previous
//
#include <hip/hip_runtime.h>

// Correlation via bf16 MFMA banded Gram.
// out[b, dyp*21+k, y, x] = (1/256) * sum_c in1[b,c,y,x] * in2[b,c,y+2(dyp-10), x+2(k-10)]
// Ag workspace: [b*64+y][par*48+col][c] bf16, x = 2*col+par.
// R8: prepass transposes in1 ONLY (high occupancy, small tiles); main kernel
// packs B from raw fp32 in2 in-block; 512-thread main, 2-phase scr -> 2 blk/CU.

typedef short bf16x8 __attribute__((ext_vector_type(8)));
typedef float f32x4  __attribute__((ext_vector_type(4)));

#define PLANE 24576         // shorts per (b,y) Ag plane: 96 rows * 256 c
#define BP    260           // B LDS row stride in shorts (payload 256 + pad 4)

__device__ __forceinline__ short f2bf(float f) {
    union { float f; unsigned u; } x; x.f = f;
    const unsigned u = x.u;
    return (short)((u + 0x7fffu + ((u >> 16) & 1u)) >> 16);
}

// ---------- prepass: fp32 in1 [b][c][y][x] -> bf16 Ag [b*64+y][par*48+col][c] ----------
// block = (b, ytile of 4, ctile of 32): 512 blocks, 30.7 KB LDS -> 5 blocks/CU.
// LDS: 384 xx-rows, stride 40 shorts, 4 cells of 8 shorts; cell col = g ^ (f&3).
__global__ __launch_bounds__(256)
void corr_prepass(const float* __restrict__ in1, short* __restrict__ dst) {
    const int bid = blockIdx.x;              // [0,512)
    const int b   = bid >> 7;
    const int yt  = (bid >> 3) & 15;
    const int ct  = bid & 7;
    const int c0 = ct * 32, y0 = yt * 4;

    __shared__ __align__(16) short T[384 * 40];   // 30720 B
    const int tid = threadIdx.x;

    // write phase: 384 slots; each converts 8 channels x 1 float4 -> 4 rows
#pragma unroll
    for (int it = 0; it < 2; ++it) {
        const int d = it * 256 + tid;
        if (d < 384) {
            const int g = d / 96;                // channel octet 0..3
            const int f = d - g * 96;            // float4 index in 4y*96x (xx0 = 4f)
            const int yy = f / 24;
            const int xf = 4 * (f - yy * 24);
            float4 v[8];
#pragma unroll
            for (int j = 0; j < 8; ++j) {
                const int c = c0 + g * 8 + j;
                v[j] = *(const float4*)(in1 + ((size_t)(b * 256 + c) * 64 + y0 + yy) * 96 + xf);
            }
            bf16x8 w0, w1, w2, w3;
#pragma unroll
            for (int j = 0; j < 8; ++j) {
                w0[j] = f2bf(v[j].x); w1[j] = f2bf(v[j].y);
                w2[j] = f2bf(v[j].z); w3[j] = f2bf(v[j].w);
            }
            const int pc = g ^ (f & 3);          // (xx>>2)&3 == f&3 for rows 4f..4f+3
            const int a0 = (4 * f) * 40 + pc * 8;
            *(bf16x8*)&T[a0]       = w0;
            *(bf16x8*)&T[a0 + 40]  = w1;
            *(bf16x8*)&T[a0 + 80]  = w2;
            *(bf16x8*)&T[a0 + 120] = w3;
        }
    }
    __syncthreads();

    // read phase: dense cell sweep, permuted-but-dense global store
#pragma unroll
    for (int it = 0; it < 6; ++it) {
        const int D  = it * 256 + tid;           // [0,1536)
        const int xx = D >> 2;
        const int pc = D & 3;
        const int cx = pc ^ ((xx >> 2) & 3);     // logical channel octet
        const bf16x8 w = *(const bf16x8*)&T[xx * 40 + pc * 8];
        const int yy = xx / 96;
        const int x  = xx - yy * 96;
        const int rl = (x & 1) * 48 + (x >> 1);  // par*48+col
        const size_t Rg = (size_t)(b * 64 + y0 + yy) * 96 + rl;
        *(bf16x8*)(dst + Rg * 256 + c0 + cx * 8) = w;
    }
}

// ---------- main: 512 threads = 8 waves = 4 dyp-slots x 2 parities ----------
__global__ __launch_bounds__(512, 4)
void corr_mfma(const short* __restrict__ Ag, const float* __restrict__ in2,
               float* __restrict__ out) {
    const int bid = blockIdx.x;                  // [0,512)
    const int pg  = bid >> 8;                    // 0..1
    const int by2 = bid & 255;
    const int b = by2 >> 6, y2 = by2 & 63;
    const int p0 = pg * 3, p1 = p0 + 3;          // dyp = 4p+slot

    const int tid  = threadIdx.x;
    const int lane = tid & 63, w = tid >> 6;     // w 0..7
    const int par  = w & 1, slot = w >> 1;       // slot 0..3
    const int n    = lane & 15, q = lane >> 4;

    __shared__ __align__(16) short Bsh[96 * BP];     // 49920 B
    __shared__ __align__(16) float scr[2][21 * 97];  // 16296 B (total 66216 B)

    // stage B(b,y2) from raw fp32 in2: fused convert + parity-pack transpose
#pragma unroll
    for (int it = 0; it < 2; ++it) {
        const int d = it * 512 + tid;            // [0,1024), valid < 768
        if (d < 768) {
            const int g = d / 24;                // channel octet 0..31
            const int f = d - g * 24;            // float4 idx along x
            float4 v[8];
#pragma unroll
            for (int j = 0; j < 8; ++j) {
                const int c = g * 8 + j;
                v[j] = *(const float4*)(in2 + ((size_t)(b * 256 + c) * 64 + y2) * 96 + 4 * f);
            }
            bf16x8 w0, w1, w2, w3;
#pragma unroll
            for (int j = 0; j < 8; ++j) {
                w0[j] = f2bf(v[j].x); w1[j] = f2bf(v[j].y);
                w2[j] = f2bf(v[j].z); w3[j] = f2bf(v[j].w);
            }
            // x = 4f+r -> rl = (x&1)*48 + (x>>1)
            *(bf16x8*)&Bsh[(2 * f)          * BP + g * 8] = w0;   // x=4f
            *(bf16x8*)&Bsh[(48 + 2 * f)     * BP + g * 8] = w1;   // x=4f+1
            *(bf16x8*)&Bsh[(2 * f + 1)      * BP + g * 8] = w2;   // x=4f+2
            *(bf16x8*)&Bsh[(48 + 2 * f + 1) * BP + g * 8] = w3;   // x=4f+3
        }
    }
    __syncthreads();

    const bool v0 = (n >= 10), v3 = (n < 10);
    const int  r0c = v0 ? (n - 10) : 0;
    const int  r3c = v3 ? (n + 38) : 0;
    const short* Bp = &Bsh[par * 48 * BP];

    for (int p = p0; p < p1; ++p) {
        const int dyp = 4 * p + slot;
        const int y   = y2 + 20 - 2 * dyp;
        const bool live = (dyp < 21) && (y >= 0) && (y < 64);

        f32x4 acc[9];
#pragma unroll
        for (int t2 = 0; t2 < 9; ++t2) acc[t2] = (f32x4)0.0f;

        if (live) {
            // A-fragments direct from global (L2/L3-resident Ag)
            const short* Ap = Ag + ((size_t)(b * 64 + y) * 96 + par * 48) * 256;
            bf16x8 af[3][8];
#pragma unroll
            for (int ks = 0; ks < 8; ++ks)
#pragma unroll
                for (int Xi = 0; Xi < 3; ++Xi)
                    af[Xi][ks] = *(const bf16x8*)(Ap + (Xi * 16 + n) * 256 + ks * 32 + q * 8);

#pragma unroll
            for (int ks = 0; ks < 8; ++ks) {
                const int ko = ks * 32 + q * 8;
                bf16x8 b0 = *(const bf16x8*)&Bp[r0c * BP + ko];     if (!v0) b0 = 0;
                bf16x8 b1 = *(const bf16x8*)&Bp[(n + 6)  * BP + ko];
                bf16x8 b2 = *(const bf16x8*)&Bp[(n + 22) * BP + ko];
                bf16x8 b3 = *(const bf16x8*)&Bp[r3c * BP + ko];     if (!v3) b3 = 0;
                acc[0] = __builtin_amdgcn_mfma_f32_16x16x32_bf16(af[0][ks], b0, acc[0], 0, 0, 0);
                acc[1] = __builtin_amdgcn_mfma_f32_16x16x32_bf16(af[0][ks], b1, acc[1], 0, 0, 0);
                acc[2] = __builtin_amdgcn_mfma_f32_16x16x32_bf16(af[0][ks], b2, acc[2], 0, 0, 0);
                acc[3] = __builtin_amdgcn_mfma_f32_16x16x32_bf16(af[1][ks], b1, acc[3], 0, 0, 0);
                acc[4] = __builtin_amdgcn_mfma_f32_16x16x32_bf16(af[1][ks], b2, acc[4], 0, 0, 0);
                acc[5] = __builtin_amdgcn_mfma_f32_16x16x32_bf16(af[1][ks], b3, acc[5], 0, 0, 0);
                acc[6] = __builtin_amdgcn_mfma_f32_16x16x32_bf16(af[2][ks], b2, acc[6], 0, 0, 0);
                acc[7] = __builtin_amdgcn_mfma_f32_16x16x32_bf16(af[2][ks], b3, acc[7], 0, 0, 0);
                // acc[8] = (X2,U4): B cols all OOB -> stays zero (true zero outputs)
            }
        }

        // ---- two-phase transpose+store through scr[2] ----
#pragma unroll
        for (int ph = 0; ph < 2; ++ph) {
            if (live && (slot >> 1) == ph) {
                float* sc = scr[slot & 1];
                const int mb = q * 4;
#pragma unroll
                for (int t2 = 0; t2 < 9; ++t2) {
                    const int Xi = (t2 < 3) ? 0 : (t2 < 6 ? 1 : 2);
                    constexpr int UJ[9] = {0, 1, 2, 1, 2, 3, 2, 3, 4};
                    const int ub = UJ[t2] * 16;
#pragma unroll
                    for (int rr = 0; rr < 4; ++rr) {
                        const int xe = Xi * 16 + mb + rr;
                        const int k  = ub + n - xe;
                        if ((unsigned)k < 21u)
                            sc[k * 97 + 2 * xe + par] = acc[t2][rr];
                    }
                }
            }
            __syncthreads();
#pragma unroll
            for (int it = 0; it < 8; ++it) {
                const int e = it * 512 + tid;    // [0,4096), valid < 4032
                if (e < 4032) {
                    const int s  = e / 2016;
                    const int f  = e - s * 2016;
                    const int k  = f / 96;
                    const int x  = f - k * 96;
                    const int dd = 4 * p + 2 * ph + s;
                    const int yd = y2 + 20 - 2 * dd;
                    if (dd < 21 && yd >= 0 && yd < 64)
                        out[((size_t)(b * 441 + dd * 21 + k) * 64 + yd) * 96 + x] =
                            scr[s][k * 97 + x] * (1.0f / 256.0f);
                }
            }
            __syncthreads();
        }
    }
}

extern "C" void kernel_launch(void* const* d_in, const int* in_sizes, int n_in,
                              void* d_out, int out_size, void* d_ws, size_t ws_size,
                              hipStream_t stream) {
    const float* in1 = (const float*)d_in[0];
    const float* in2 = (const float*)d_in[1];
    float* out = (float*)d_out;

    short* Ag = (short*)d_ws;                    // 256 planes * 24576 shorts = 12.58 MB

    corr_prepass<<<dim3(512), dim3(256), 0, stream>>>(in1, Ag);
    corr_mfma<<<dim3(512), dim3(512), 0, stream>>>(Ag, in2, out);
}

// Round 10
// 178.712 us; speedup vs baseline: 1.2074x; 1.1537x over previous
//
#include <hip/hip_runtime.h>

// Correlation via bf16 MFMA banded Gram — SINGLE kernel, no workspace.
// out[b, dyp*21+k, y, x] = (1/256) * sum_c in1[b,c,y,x] * in2[b,c,y+2(dyp-10), x+2(k-10)]
// Parity split: x = 2*col+par. Per block (b, y2=in2-row, pg):
//   B(b,y2) fp32 -> bf16 packed into LDS once (R8-verified);
//   A-fragments gathered inline from raw fp32 in1 (scalar loads at lane-fixed x,
//   8 contiguous-in-c elements per fragment) -> no prepass, no grid sync.

typedef short bf16x8 __attribute__((ext_vector_type(8)));
typedef float f32x4  __attribute__((ext_vector_type(4)));

#define BP 260              // B LDS row stride in shorts (payload 256 + pad 4)

__device__ __forceinline__ short f2bf(float f) {
    union { float f; unsigned u; } x; x.f = f;
    const unsigned u = x.u;
    return (short)((u + 0x7fffu + ((u >> 16) & 1u)) >> 16);
}

__global__ __launch_bounds__(256, 2)
void corr_one(const float* __restrict__ in1, const float* __restrict__ in2,
              float* __restrict__ out) {
    const int bid = blockIdx.x;                  // [0,512)
    const int pg  = bid >> 8;                    // 0..1
    const int by2 = bid & 255;
    const int b = by2 >> 6, y2 = by2 & 63;
    const int p0 = pg ? 6 : 0, p1 = pg ? 11 : 6; // dyp = 2p+slot covers 0..20

    const int tid  = threadIdx.x;
    const int lane = tid & 63, w = tid >> 6;     // w 0..3
    const int par  = w & 1, slot = w >> 1;       // slot 0..1
    const int n    = lane & 15, q = lane >> 4;

    __shared__ __align__(16) short Bsh[96 * BP];     // 49920 B
    __shared__ __align__(16) float scr[2][21 * 97];  // 16296 B (total 66216 B)

    // ---- stage B(b,y2) from raw fp32 in2: fused convert + parity-pack (R8) ----
#pragma unroll
    for (int it = 0; it < 3; ++it) {
        const int d = it * 256 + tid;            // [0,768)
        const int g = d / 24;                    // channel octet 0..31
        const int f = d - g * 24;                // float4 idx along x
        float4 v[8];
#pragma unroll
        for (int j = 0; j < 8; ++j)
            v[j] = *(const float4*)(in2 + ((size_t)(b * 256 + g * 8 + j) * 64 + y2) * 96 + 4 * f);
        bf16x8 w0, w1, w2, w3;
#pragma unroll
        for (int j = 0; j < 8; ++j) {
            w0[j] = f2bf(v[j].x); w1[j] = f2bf(v[j].y);
            w2[j] = f2bf(v[j].z); w3[j] = f2bf(v[j].w);
        }
        // x = 4f+r -> rl = (x&1)*48 + (x>>1)
        *(bf16x8*)&Bsh[(2 * f)          * BP + g * 8] = w0;   // x=4f
        *(bf16x8*)&Bsh[(48 + 2 * f)     * BP + g * 8] = w1;   // x=4f+1
        *(bf16x8*)&Bsh[(2 * f + 1)      * BP + g * 8] = w2;   // x=4f+2
        *(bf16x8*)&Bsh[(48 + 2 * f + 1) * BP + g * 8] = w3;   // x=4f+3
    }
    __syncthreads();

    const bool v0 = (n >= 10), v3 = (n < 10);
    const int  r0c = v0 ? (n - 10) : 0;
    const int  r3c = v3 ? (n + 38) : 0;
    const short* Bp = &Bsh[par * 48 * BP];

    const int xoff = 2 * n + par;                // x for Xi=0; Xi adds 32 floats

    for (int p = p0; p < p1; ++p) {
        const int dyp = 2 * p + slot;
        const int y   = y2 + 20 - 2 * dyp;
        const bool live = (dyp < 21) && (y >= 0) && (y < 64);

        f32x4 acc[9];
#pragma unroll
        for (int t2 = 0; t2 < 9; ++t2) acc[t2] = (f32x4)0.0f;

        if (live) {
            // A row base for this (b, y): channel c lives at + c*6144
            const float* Arow = in1 + ((size_t)(b * 256) * 64 + y) * 96 + xoff;

#pragma unroll 2
            for (int ks = 0; ks < 8; ++ks) {
                // inline A-fragment gather: 24 scalar fp32 loads + convert/pack
                bf16x8 a0v, a1v, a2v;
#pragma unroll
                for (int j = 0; j < 8; ++j) {
                    const float* Ac = Arow + (size_t)(ks * 32 + q * 8 + j) * 6144;
                    a0v[j] = f2bf(Ac[0]);        // Xi=0: x = 2n+par
                    a1v[j] = f2bf(Ac[32]);       // Xi=1: x = 2(16+n)+par
                    a2v[j] = f2bf(Ac[64]);       // Xi=2: x = 2(32+n)+par
                }
                const int ko = ks * 32 + q * 8;
                bf16x8 b0 = *(const bf16x8*)&Bp[r0c * BP + ko];     if (!v0) b0 = 0;
                bf16x8 b1 = *(const bf16x8*)&Bp[(n + 6)  * BP + ko];
                bf16x8 b2 = *(const bf16x8*)&Bp[(n + 22) * BP + ko];
                bf16x8 b3 = *(const bf16x8*)&Bp[r3c * BP + ko];     if (!v3) b3 = 0;
                acc[0] = __builtin_amdgcn_mfma_f32_16x16x32_bf16(a0v, b0, acc[0], 0, 0, 0);
                acc[1] = __builtin_amdgcn_mfma_f32_16x16x32_bf16(a0v, b1, acc[1], 0, 0, 0);
                acc[2] = __builtin_amdgcn_mfma_f32_16x16x32_bf16(a0v, b2, acc[2], 0, 0, 0);
                acc[3] = __builtin_amdgcn_mfma_f32_16x16x32_bf16(a1v, b1, acc[3], 0, 0, 0);
                acc[4] = __builtin_amdgcn_mfma_f32_16x16x32_bf16(a1v, b2, acc[4], 0, 0, 0);
                acc[5] = __builtin_amdgcn_mfma_f32_16x16x32_bf16(a1v, b3, acc[5], 0, 0, 0);
                acc[6] = __builtin_amdgcn_mfma_f32_16x16x32_bf16(a2v, b2, acc[6], 0, 0, 0);
                acc[7] = __builtin_amdgcn_mfma_f32_16x16x32_bf16(a2v, b3, acc[7], 0, 0, 0);
                // acc[8] = (X2,U4): all B cols OOB -> stays zero (true zero outputs)
            }

            // scatter C tiles into scratch at (k, x=2*xe+par)
            float* sc = scr[slot];
            const int mb = q * 4;
#pragma unroll
            for (int t2 = 0; t2 < 9; ++t2) {
                const int Xi = (t2 < 3) ? 0 : (t2 < 6 ? 1 : 2);
                constexpr int UJ[9] = {0, 1, 2, 1, 2, 3, 2, 3, 4};
                const int ub = UJ[t2] * 16;
#pragma unroll
                for (int rr = 0; rr < 4; ++rr) {
                    const int xe = Xi * 16 + mb + rr;
                    const int k  = ub + n - xe;
                    if ((unsigned)k < 21u)
                        sc[k * 97 + 2 * xe + par] = acc[t2][rr];
                }
            }
        }
        __syncthreads();

        // cooperative coalesced store of both slots' dyps
#pragma unroll
        for (int it = 0; it < 16; ++it) {
            const int e = it * 256 + tid;        // [0,4096), valid < 4032
            if (e < 4032) {
                const int s  = e / 2016;
                const int f  = e - s * 2016;
                const int k  = f / 96;
                const int x  = f - k * 96;
                const int dd = 2 * p + s;
                const int yd = y2 + 20 - 2 * dd;
                if (dd < 21 && yd >= 0 && yd < 64)
                    out[((size_t)(b * 441 + dd * 21 + k) * 64 + yd) * 96 + x] =
                        scr[s][k * 97 + x] * (1.0f / 256.0f);
            }
        }
        __syncthreads();
    }
}

extern "C" void kernel_launch(void* const* d_in, const int* in_sizes, int n_in,
                              void* d_out, int out_size, void* d_ws, size_t ws_size,
                              hipStream_t stream) {
    const float* in1 = (const float*)d_in[0];
    const float* in2 = (const float*)d_in[1];
    float* out = (float*)d_out;

    corr_one<<<dim3(512), dim3(256), 0, stream>>>(in1, in2, out);
}